// Round 2
// baseline (236.197 us; speedup 1.0000x reference)
//
#include <hip/hip_runtime.h>

#define DIMN 32
#define HD   32
#define FN   16
#define FE   8
#define NG   64

// K1: per-node precompute (+ zero the CSR histogram counters).
//   out[n,d]   = relu(x[n,:] @ lin0_w[d,:] + lin0_b[d])
//   G[n,h,f]   = sum_d out[n,d] * nn_w[(d*32+h)*8 + f]   (stored n*256 + h*8 + f)
//   bmsg[n,h]  = sum_d out[n,d] * nn_b[d*32+h]
__global__ __launch_bounds__(256) void k1_node_pre(
    const float* __restrict__ x, const float* __restrict__ lin0_w,
    const float* __restrict__ lin0_b, const float* __restrict__ nn_w,
    const float* __restrict__ nn_b,
    float* __restrict__ outn, float* __restrict__ G, float* __restrict__ bmsg,
    int* __restrict__ cnt,
    int N, int nodes_per_block)
{
    // nn_w global layout: index (d*32+h)*8+f = d*256 + tid -> conflict-free LDS reads.
    __shared__ float s_nnw[DIMN * HD * FE];  // 32 KB
    __shared__ float s_nnb[DIMN * HD];
    __shared__ float s_l0w[DIMN * FN];
    __shared__ float s_l0b[DIMN];
    __shared__ float s_out[DIMN];

    const int tid = threadIdx.x;
    // fold CSR-counter zeroing into this kernel (runs before k_hist on the stream)
    const int gz = blockIdx.x * 256 + tid;
    if (gz < N) cnt[gz] = 0;

    for (int i = tid; i < DIMN * HD * FE; i += 256) s_nnw[i] = nn_w[i];
    for (int i = tid; i < DIMN * HD; i += 256)      s_nnb[i] = nn_b[i];
    for (int i = tid; i < DIMN * FN; i += 256)      s_l0w[i] = lin0_w[i];
    if (tid < DIMN) s_l0b[tid] = lin0_b[tid];
    __syncthreads();

    const int n0 = blockIdx.x * nodes_per_block;
    const int n1 = min(n0 + nodes_per_block, N);
    for (int n = n0; n < n1; ++n) {
        if (tid < DIMN) {
            float s = s_l0b[tid];
            const float* xr = x + (size_t)n * FN;
            #pragma unroll
            for (int j = 0; j < FN; ++j) s = fmaf(xr[j], s_l0w[tid * FN + j], s);
            s = fmaxf(s, 0.f);
            s_out[tid] = s;
            outn[(size_t)n * DIMN + tid] = s;
        }
        __syncthreads();

        float g = 0.f;
        #pragma unroll 8
        for (int d = 0; d < DIMN; ++d)
            g = fmaf(s_out[d], s_nnw[d * 256 + tid], g);
        G[(size_t)n * 256 + tid] = g;

        if (tid < HD) {
            float b = 0.f;
            #pragma unroll 8
            for (int d = 0; d < DIMN; ++d)
                b = fmaf(s_out[d], s_nnb[d * HD + tid], b);
            bmsg[(size_t)n * HD + tid] = b;
        }
        __syncthreads();
    }
}

// CSR build: histogram of dst
__global__ __launch_bounds__(256) void k_hist(
    const int* __restrict__ ei, int* __restrict__ cnt, int E)
{
    const int e = blockIdx.x * 256 + threadIdx.x;
    if (e < E) atomicAdd(&cnt[ei[E + e]], 1);
}

// CSR build: single-block exclusive scan over cnt[0..N) -> offs, cur
__global__ __launch_bounds__(256) void k_scan(
    const int* __restrict__ cnt, int* __restrict__ offs, int* __restrict__ cur, int N)
{
    __shared__ int s[256];
    const int tid = threadIdx.x;
    const int C = (N + 255) / 256;
    const int lo = tid * C, hi = min(lo + C, N);
    int sum = 0;
    for (int i = lo; i < hi; ++i) sum += cnt[i];
    s[tid] = sum;
    __syncthreads();
    // Hillis-Steele inclusive scan over 256 partials
    for (int off = 1; off < 256; off <<= 1) {
        int v = (tid >= off) ? s[tid - off] : 0;
        __syncthreads();
        s[tid] += v;
        __syncthreads();
    }
    int run = (tid == 0) ? 0 : s[tid - 1];
    for (int i = lo; i < hi; ++i) {
        offs[i] = run;
        cur[i]  = run;
        run += cnt[i];
    }
    if (tid == 0) offs[N] = s[255];
}

// CSR build: scatter edge ids into dst-sorted order
__global__ __launch_bounds__(256) void k_scatter(
    const int* __restrict__ ei, int* __restrict__ cur, int* __restrict__ eids, int E)
{
    const int e = blockIdx.x * 256 + threadIdx.x;
    if (e < E) {
        int p = atomicAdd(&cur[ei[E + e]], 1);
        eids[p] = e;
    }
}

// K2: per-dst gather + message + fused root update. 32 threads per node, lane = h.
// No atomics: each group owns its output row.
__global__ __launch_bounds__(256) void k2_gather(
    const int* __restrict__ ei, const float* __restrict__ ea,
    const float* __restrict__ G, const float* __restrict__ bmsg,
    const float* __restrict__ outn, const float* __restrict__ root_w,
    const float* __restrict__ conv_b,
    const int* __restrict__ offs, const int* __restrict__ eids,
    float* __restrict__ hout, int N, int E)
{
    __shared__ float s_rw[DIMN * HD];
    __shared__ float s_cb[HD];
    const int tid = threadIdx.x;
    for (int i = tid; i < DIMN * HD; i += 256) s_rw[i] = root_w[i];
    if (tid < HD) s_cb[tid] = conv_b[tid];
    __syncthreads();

    const int t = blockIdx.x * 256 + tid;
    const int n = t >> 5;
    const int h = t & 31;
    if (n >= N) return;

    float acc = 0.f;
    const int lo = offs[n], hi = offs[n + 1];
    for (int j = lo; j < hi; ++j) {
        const int e   = eids[j];
        const int src = ei[e];
        const float* gp = G + (size_t)src * 256 + h * 8;
        const float4 ga = *(const float4*)(gp);
        const float4 gb = *(const float4*)(gp + 4);
        const float4 e0 = *(const float4*)(ea + (size_t)e * 8);
        const float4 e1 = *(const float4*)(ea + (size_t)e * 8 + 4);
        float m = bmsg[(size_t)src * HD + h];
        m = fmaf(e0.x, ga.x, m);
        m = fmaf(e0.y, ga.y, m);
        m = fmaf(e0.z, ga.z, m);
        m = fmaf(e0.w, ga.w, m);
        m = fmaf(e1.x, gb.x, m);
        m = fmaf(e1.y, gb.y, m);
        m = fmaf(e1.z, gb.z, m);
        m = fmaf(e1.w, gb.w, m);
        acc += m;
    }

    // fused: h = relu(agg + out @ root_w + conv_b)
    float v = acc + s_cb[h];
    const float* orow = outn + (size_t)n * DIMN;
    #pragma unroll 8
    for (int k = 0; k < DIMN; ++k)
        v = fmaf(orow[k], s_rw[k * HD + h], v);
    hout[(size_t)n * HD + h] = fmaxf(v, 0.f);
}

// K4: pool (batch is sorted -> contiguous per-graph ranges, no atomics) + head MLP.
__global__ __launch_bounds__(64) void k4_pool_head(
    const float* __restrict__ hout, const int* __restrict__ batch,
    const float* __restrict__ lin1_w, const float* __restrict__ lin1_b,
    const float* __restrict__ lin2_w, const float* __restrict__ lin2_b,
    float* __restrict__ outp, int N)
{
    const int g = blockIdx.x;
    const int tid = threadIdx.x;

    // uniform binary searches for this graph's node range
    int a = 0, b = N;
    while (a < b) { int m = (a + b) >> 1; if (batch[m] < g) a = m + 1; else b = m; }
    const int lo = a;
    b = N;
    while (a < b) { int m = (a + b) >> 1; if (batch[m] < g + 1) a = m + 1; else b = m; }
    const int hi = a;

    __shared__ float s_u[HD];
    __shared__ float s_o[16];

    const int h = tid & 31, half = tid >> 5;
    float s = 0.f;
    for (int n = lo + half; n < hi; n += 2)
        s += hout[(size_t)n * HD + h];
    s += __shfl_down(s, 32);
    if (tid < HD) s_u[tid] = s;
    __syncthreads();

    if (tid < 16) {
        float o = lin1_b[tid];
        #pragma unroll
        for (int k = 0; k < HD; ++k) o = fmaf(s_u[k], lin1_w[tid * HD + k], o);
        s_o[tid] = fmaxf(o, 0.f);
    }
    __syncthreads();

    if (tid == 0) {
        float acc = lin2_b[0];
        #pragma unroll
        for (int i = 0; i < 16; ++i) acc = fmaf(s_o[i], lin2_w[i], acc);
        outp[g] = acc;
    }
}

extern "C" void kernel_launch(void* const* d_in, const int* in_sizes, int n_in,
                              void* d_out, int out_size, void* d_ws, size_t ws_size,
                              hipStream_t stream)
{
    const float* x      = (const float*)d_in[0];
    const int*   ei     = (const int*)  d_in[1];
    const float* ea     = (const float*)d_in[2];
    const int*   batch  = (const int*)  d_in[3];
    const float* lin0_w = (const float*)d_in[4];
    const float* lin0_b = (const float*)d_in[5];
    const float* nn_w   = (const float*)d_in[6];
    const float* nn_b   = (const float*)d_in[7];
    const float* root_w = (const float*)d_in[8];
    const float* conv_b = (const float*)d_in[9];
    const float* lin1_w = (const float*)d_in[10];
    const float* lin1_b = (const float*)d_in[11];
    const float* lin2_w = (const float*)d_in[12];
    const float* lin2_b = (const float*)d_in[13];

    const int N = in_sizes[0] / FN;   // 12500
    const int E = in_sizes[2] / FE;   // 200000

    float* ws   = (float*)d_ws;
    float* outn = ws;                          // N*32
    float* G    = outn + (size_t)N * DIMN;     // N*256
    float* bmsg = G    + (size_t)N * 256;      // N*32
    float* hout = bmsg + (size_t)N * DIMN;     // N*32
    int*   cnt  = (int*)(hout + (size_t)N * DIMN);  // N
    int*   offs = cnt  + N;                    // N+1
    int*   cur  = offs + N + 1;                // N
    int*   eids = cur  + N;                    // E

    const int npb = 16;
    const int nb1 = (N + npb - 1) / npb;
    k1_node_pre<<<nb1, 256, 0, stream>>>(x, lin0_w, lin0_b, nn_w, nn_b,
                                         outn, G, bmsg, cnt, N, npb);

    const int nbe = (E + 255) / 256;
    k_hist<<<nbe, 256, 0, stream>>>(ei, cnt, E);
    k_scan<<<1, 256, 0, stream>>>(cnt, offs, cur, N);
    k_scatter<<<nbe, 256, 0, stream>>>(ei, cur, eids, E);

    const int nb2 = (N * 32 + 255) / 256;
    k2_gather<<<nb2, 256, 0, stream>>>(ei, ea, G, bmsg, outn, root_w, conv_b,
                                       offs, eids, hout, N, E);

    k4_pool_head<<<NG, 64, 0, stream>>>(hout, batch, lin1_w, lin1_b,
                                        lin2_w, lin2_b, (float*)d_out, N);
}